// Round 7
// baseline (3761.580 us; speedup 1.0000x reference)
//
#include <hip/hip_runtime.h>

typedef _Float16 half8 __attribute__((ext_vector_type(8)));
typedef _Float16 half4 __attribute__((ext_vector_type(4)));
typedef float floatx4 __attribute__((ext_vector_type(4)));

static constexpr int BATCH = 1024;
static constexpr int NIN   = 512;    // in_features
static constexpr int MOUT  = 1024;   // out_features
static constexpr float LAMBD = 0.2f;
static constexpr float TOLF  = 1e-4f;
static constexpr int MAX_ITERS = 100;
static constexpr int MM = BATCH * MOUT;   // 1M elements

// Fragment-swizzled layout for 16x16x32 MFMA operands (A: rows, B: cols), f16:
//   flat = ((tile16*32 + kchunk32)*64 + lane)*8 + elem
//   lane = (idx&15) | (((k>>3)&3)<<4), elem = k&7
// K is always 1024 here (32 k-chunks). A wave loads one 16(x)x32(k) fragment
// as one coalesced 16B/lane load.
__device__ __forceinline__ size_t swz(int idx, int k) {
    return ((((size_t)(idx >> 4) * 32 + (k >> 5)) * 64 +
             ((idx & 15) | (((k >> 3) & 3) << 4))) << 3) + (k & 7);
}

__device__ __forceinline__ float shrinkf(float t) {
    float a = fabsf(t) - LAMBD;
    return a > 0.f ? copysignf(a, t) : 0.f;
}

// ---------------------------------------------------------------------------
// zero-init: t, xk, enc, dec, swizzled enc halves, solved
// ---------------------------------------------------------------------------
__global__ __launch_bounds__(256) void zero_init(float* t, float* xk, float* enc,
                                                 float* dec, float* ench_f,
                                                 float* encl_f, int* solved) {
    int i = blockIdx.x * 256 + threadIdx.x;
    if (i < MM) { t[i] = 0.f; xk[i] = 0.f; enc[i] = 0.f; }
    if (i < MM / 2) { dec[i] = 0.f; ench_f[i] = 0.f; encl_f[i] = 0.f; }
    if (i < BATCH) solved[i] = 0;
}

// ---------------------------------------------------------------------------
// Th/Tl = B-fragment-swizzled split-f16 of Minv (col=n in 1024, k in 1024).
// ---------------------------------------------------------------------------
__global__ __launch_bounds__(256) void split_minv(const float* __restrict__ Minv,
                                                  _Float16* __restrict__ Th,
                                                  _Float16* __restrict__ Tl) {
    int g = blockIdx.x * 256 + threadIdx.x;   // 131072 threads
    int n = g & 1023, k0 = (g >> 10) << 3;
    half8 h, l;
    #pragma unroll
    for (int e = 0; e < 8; ++e) {
        float val = Minv[(size_t)(k0 + e) * MOUT + n];
        _Float16 hh = (_Float16)val;
        h[e] = hh;
        l[e] = (_Float16)(val - (float)hh);
    }
    size_t off = swz(n, k0);
    *(half8*)&Th[off] = h;
    *(half8*)&Tl[off] = l;
}

// ---------------------------------------------------------------------------
// wsh/wsl = B-fragment-swizzled split-f16 of weight (col=n in 512, k in 1024).
// weight[k][n] row-major with row stride NIN.
// ---------------------------------------------------------------------------
__global__ __launch_bounds__(256) void split_w(const float* __restrict__ w,
                                               _Float16* __restrict__ wsh,
                                               _Float16* __restrict__ wsl) {
    int g = blockIdx.x * 256 + threadIdx.x;   // 65536 threads
    int n = g & 511, k0 = (g >> 9) << 3;
    half8 h, l;
    #pragma unroll
    for (int e = 0; e < 8; ++e) {
        float val = w[(size_t)(k0 + e) * NIN + n];
        _Float16 hh = (_Float16)val;
        h[e] = hh;
        l[e] = (_Float16)(val - (float)hh);
    }
    size_t off = swz(n, k0);
    *(half8*)&wsh[off] = h;
    *(half8*)&wsl[off] = l;
}

// ---------------------------------------------------------------------------
// adb = x @ w^T (fp32, once). Epilogue emits beff = adb as A-swizzled h/l.
// ---------------------------------------------------------------------------
__global__ __launch_bounds__(256) void gemm_adb(const float* __restrict__ x,
                                                const float* __restrict__ w,
                                                float* __restrict__ adb,
                                                _Float16* __restrict__ bh,
                                                _Float16* __restrict__ bl) {
    __shared__ float As[16][68];
    __shared__ float Bs[16][68];
    const int tid = threadIdx.x;
    const int i0 = (blockIdx.x >> 4) * 64, j0 = (blockIdx.x & 15) * 64;
    const int tx = tid & 15, ty = tid >> 4;
    const int lr = tid >> 2, lk = (tid & 3) << 2;
    float acc[4][4] = {};
    for (int k0 = 0; k0 < NIN; k0 += 16) {
        float4 a4 = *(const float4*)&x[(i0 + lr) * NIN + k0 + lk];
        As[lk + 0][lr] = a4.x; As[lk + 1][lr] = a4.y;
        As[lk + 2][lr] = a4.z; As[lk + 3][lr] = a4.w;
        float4 b4 = *(const float4*)&w[(j0 + lr) * NIN + k0 + lk];
        Bs[lk + 0][lr] = b4.x; Bs[lk + 1][lr] = b4.y;
        Bs[lk + 2][lr] = b4.z; Bs[lk + 3][lr] = b4.w;
        __syncthreads();
        #pragma unroll
        for (int kk = 0; kk < 16; ++kk) {
            float4 a_ = *(const float4*)&As[kk][ty << 2];
            float4 b_ = *(const float4*)&Bs[kk][tx << 2];
            #pragma unroll
            for (int r = 0; r < 4; ++r) {
                float av = r == 0 ? a_.x : r == 1 ? a_.y : r == 2 ? a_.z : a_.w;
                acc[r][0] = fmaf(av, b_.x, acc[r][0]);
                acc[r][1] = fmaf(av, b_.y, acc[r][1]);
                acc[r][2] = fmaf(av, b_.z, acc[r][2]);
                acc[r][3] = fmaf(av, b_.w, acc[r][3]);
            }
        }
        __syncthreads();
    }
    const int k4 = j0 + (tx << 2);
    #pragma unroll
    for (int r = 0; r < 4; ++r) {
        const int row = i0 + (ty << 2) + r;
        *(float4*)&adb[(size_t)row * MOUT + k4] =
            make_float4(acc[r][0], acc[r][1], acc[r][2], acc[r][3]);
        half4 h, l;
        #pragma unroll
        for (int e = 0; e < 4; ++e) {
            _Float16 hh = (_Float16)acc[r][e];
            h[e] = hh;
            l[e] = (_Float16)(acc[r][e] - (float)hh);
        }
        size_t off = swz(row, k4);
        *(half4*)&bh[off] = h;
        *(half4*)&bl[off] = l;
    }
}

// ---------------------------------------------------------------------------
// MFMA GEMM, barrier-free K-loop. Block = 128x128 tile, S=8 K-split
// (steps=4 k32-chunks each). A partition (128 rows x 128 k, h+l = 64 KB)
// staged to LDS once via global_load_lds, ONE barrier, then 4 unrolled steps
// of pure {global B loads -> ds_read A -> 48 MFMA} with no syncs.
// Epilogue: atomicAdd fp32 into out (out pre-zeroed; 8 addends/element).
// NSTR = output row stride (and N extent = NSTR). SKIP = solved-stripe skip.
// ---------------------------------------------------------------------------
template <int NSTR, bool SKIP>
__global__ __launch_bounds__(256, 2)
void mfma_gemm(const _Float16* __restrict__ Ahg, const _Float16* __restrict__ Alg,
               const _Float16* __restrict__ Bhg, const _Float16* __restrict__ Blg,
               float* __restrict__ out, const int* __restrict__ solved) {
    constexpr int NT = NSTR / 128;         // col-tiles of 128 per row
    const int bid = blockIdx.x;
    const int c = bid & 7, t = bid >> 3;   // c: K-chunk (XCD-aligned)
    const int mt = t / NT, nt = t % NT;
    const int tid = threadIdx.x, lane = tid & 63;

    if (SKIP) {
        bool done = ((volatile const int*)solved)[(mt << 7) + lane] &&
                    ((volatile const int*)solved)[(mt << 7) + 64 + lane];
        if (__ballot(done) == ~0ull) return;
    }

    __shared__ _Float16 Ash[64 * 512];     // 64 KB: chunk(rt,kc,hl) x 512 halves

    const int wv = tid >> 6;
    const int wm = (tid >> 7) & 1, wn = (tid >> 6) & 1;
    const int kf0 = c << 2;                // first k32-chunk of this partition

    // ---- stage A partition: 64 chunks of 1 KB, 16 per wave, one barrier
    #pragma unroll
    for (int i = 0; i < 16; ++i) {
        const int chunk = (wv << 4) + i;
        const int rt = chunk >> 3, kc = (chunk >> 1) & 3, hl = chunk & 1;
        const _Float16* src = (hl ? Alg : Ahg) +
            ((((size_t)((mt << 3) + rt) * 32 + kf0 + kc) << 9) + ((size_t)lane << 3));
        __builtin_amdgcn_global_load_lds(
            (const __attribute__((address_space(1))) void*)src,
            (__attribute__((address_space(3))) void*)&Ash[(size_t)chunk << 9],
            16, 0, 0);
    }
    __syncthreads();

    // ---- B pointers: 4 col-tiles per wave
    const int ct0 = nt * 8 + (wn << 2);
    const _Float16* pBh = Bhg + ((((size_t)ct0 * 32 + kf0) * 64 + lane) << 3);
    const _Float16* pBl = Blg + ((((size_t)ct0 * 32 + kf0) * 64 + lane) << 3);

    floatx4 acc[4][4] = {};
    #pragma unroll
    for (int s = 0; s < 4; ++s) {
        half8 bhf[4], blf[4];
        #pragma unroll
        for (int j = 0; j < 4; ++j) {
            bhf[j] = *(const half8*)(pBh + ((size_t)j << 14) + ((size_t)s << 9));
            blf[j] = *(const half8*)(pBl + ((size_t)j << 14) + ((size_t)s << 9));
        }
        half8 ah[4], al[4];
        #pragma unroll
        for (int i = 0; i < 4; ++i) {
            const int rt = (wm << 2) + i;
            ah[i] = *(const half8*)&Ash[((((rt << 2) + s) << 1) << 9) + (lane << 3)];
            al[i] = *(const half8*)&Ash[(((((rt << 2) + s) << 1) + 1) << 9) + (lane << 3)];
        }
        #pragma unroll
        for (int i = 0; i < 4; ++i)
            #pragma unroll
            for (int j = 0; j < 4; ++j) {
                acc[i][j] = __builtin_amdgcn_mfma_f32_16x16x32_f16(
                    ah[i], blf[j], acc[i][j], 0, 0, 0);
                acc[i][j] = __builtin_amdgcn_mfma_f32_16x16x32_f16(
                    al[i], bhf[j], acc[i][j], 0, 0, 0);
                acc[i][j] = __builtin_amdgcn_mfma_f32_16x16x32_f16(
                    ah[i], bhf[j], acc[i][j], 0, 0, 0);
            }
    }

    // C/D: col = lane&15, row = (lane>>4)*4 + reg  [m89 verified]
    const int orow = (lane >> 4) << 2;
    #pragma unroll
    for (int i = 0; i < 4; ++i) {
        const int gr = (mt << 7) + (wm << 6) + (i << 4) + orow;
        #pragma unroll
        for (int j = 0; j < 4; ++j) {
            const int gc = nt * 128 + (wn << 6) + (j << 4) + (lane & 15);
            #pragma unroll
            for (int r = 0; r < 4; ++r)
                atomicAdd(&out[(size_t)(gr + r) * NSTR + gc], acc[i][j][r]);
        }
    }
}

// ---------------------------------------------------------------------------
// Row update (t-trick): state is t = xk + u only. v_prev = shrink(t_prev),
// u = t_prev - v_prev (bitwise identical to stored values). Reads xk and
// zeroes it in place for the next iteration's atomics. Emits beff split h/l;
// at freeze writes enc (fp32) + swizzled split enc for the dec MFMA.
// 1 wave per row, shuffle-only reduction.
// ---------------------------------------------------------------------------
__global__ __launch_bounds__(256) void update(const float* __restrict__ adb,
                                              float* __restrict__ xk,
                                              float* __restrict__ t,
                                              _Float16* __restrict__ bh,
                                              _Float16* __restrict__ bl,
                                              float* __restrict__ enc,
                                              _Float16* __restrict__ ench,
                                              _Float16* __restrict__ encl,
                                              int* solved) {
    const int tid = threadIdx.x, lane = tid & 63;
    const int row = (blockIdx.x << 2) + (tid >> 6);
    if (((volatile const int*)solved)[row]) return;   // wave-uniform

    float vn[16];
    float dx2 = 0.f, x2 = 0.f;
    #pragma unroll
    for (int cch = 0; cch < 4; ++cch) {
        const int k4 = (cch << 8) + (lane << 2);
        const size_t j = ((size_t)row << 10) + k4;
        float4 kx = *(const float4*)&xk[j];
        *(float4*)&xk[j] = make_float4(0.f, 0.f, 0.f, 0.f);
        float4 tp = *(const float4*)&t[j];
        float4 aa = *(const float4*)&adb[j];
        float kxa[4] = {kx.x, kx.y, kx.z, kx.w};
        float tpa[4] = {tp.x, tp.y, tp.z, tp.w};
        float aaa[4] = {aa.x, aa.y, aa.z, aa.w};
        float tna[4];
        half4 h, l;
        #pragma unroll
        for (int e = 0; e < 4; ++e) {
            float vprev = shrinkf(tpa[e]);
            float uu = tpa[e] - vprev;
            float tn = kxa[e] + uu;
            float vv = shrinkf(tn);
            float d = vv - vprev;
            dx2 += d * d;
            x2 += vv * vv;
            vn[(cch << 2) + e] = vv;
            tna[e] = tn;
            float nb = aaa[e] + 2.f * vv - tn;   // adb + v_new - u_new
            _Float16 hh = (_Float16)nb;
            h[e] = hh;
            l[e] = (_Float16)(nb - (float)hh);
        }
        *(float4*)&t[j] = make_float4(tna[0], tna[1], tna[2], tna[3]);
        size_t off = swz(row, k4);
        *(half4*)&bh[off] = h;
        *(half4*)&bl[off] = l;
    }
    #pragma unroll
    for (int off = 32; off; off >>= 1) {
        dx2 += __shfl_xor(dx2, off);
        x2  += __shfl_xor(x2, off);
    }
    if (dx2 < TOLF * TOLF * x2) {   // x2==0 -> false (NaN semantics)
        #pragma unroll
        for (int cch = 0; cch < 4; ++cch) {
            const int k4 = (cch << 8) + (lane << 2);
            const size_t j = ((size_t)row << 10) + k4;
            float a0 = vn[(cch << 2) + 0], a1 = vn[(cch << 2) + 1];
            float a2 = vn[(cch << 2) + 2], a3 = vn[(cch << 2) + 3];
            *(float4*)&enc[j] = make_float4(a0, a1, a2, a3);
            half4 h, l;
            float va[4] = {a0, a1, a2, a3};
            #pragma unroll
            for (int e = 0; e < 4; ++e) {
                _Float16 hh = (_Float16)va[e];
                h[e] = hh;
                l[e] = (_Float16)(va[e] - (float)hh);
            }
            size_t off = swz(row, k4);
            *(half4*)&ench[off] = h;
            *(half4*)&encl[off] = l;
        }
        if (lane == 0) ((volatile int*)solved)[row] = 1;
    }
}

// ---------------------------------------------------------------------------
extern "C" void kernel_launch(void* const* d_in, const int* in_sizes, int n_in,
                              void* d_out, int out_size, void* d_ws, size_t ws_size,
                              hipStream_t stream) {
    const float* x    = (const float*)d_in[0];
    const float* w    = (const float*)d_in[1];
    const float* Minv = (const float*)d_in[2];

    float* enc = (float*)d_out;          // encoded: 1024*1024
    float* dec = enc + MM;               // decoded: 1024*512

    // ws (floats): adb MM | t MM | xk MM | halves: bh,bl,Th,Tl,ench,encl MM each,
    // wsh,wsl 512K each | solved. Total ~26 MB.
    float* ws  = (float*)d_ws;
    float* adb = ws;
    float* t   = ws + (size_t)MM;
    float* xk  = ws + 2 * (size_t)MM;

    _Float16* bh   = (_Float16*)(ws + 3 * (size_t)MM);
    _Float16* bl   = bh + (size_t)MM;
    _Float16* Th   = bl + (size_t)MM;
    _Float16* Tl   = Th + (size_t)MM;
    _Float16* ench = Tl + (size_t)MM;
    _Float16* encl = ench + (size_t)MM;
    _Float16* wsh  = encl + (size_t)MM;
    _Float16* wsl  = wsh + (size_t)(NIN * MOUT);
    int* solved    = (int*)(wsl + (size_t)(NIN * MOUT));

    zero_init<<<(MM + 255) / 256, 256, 0, stream>>>(t, xk, enc, dec,
                                                    (float*)ench, (float*)encl,
                                                    solved);
    split_minv<<<512, 256, 0, stream>>>(Minv, Th, Tl);
    split_w<<<256, 256, 0, stream>>>(w, wsh, wsl);
    gemm_adb<<<256, 256, 0, stream>>>(x, w, adb, bh, bl);

    for (int it = 0; it < MAX_ITERS; ++it) {
        mfma_gemm<MOUT, true><<<512, 256, 0, stream>>>(bh, bl, Th, Tl, xk, solved);
        update<<<256, 256, 0, stream>>>(adb, xk, t, bh, bl, enc, ench, encl,
                                        solved);
    }

    // dec = enc @ w via the same MFMA kernel (M=1024, N=512, K=1024, S=8)
    mfma_gemm<NIN, false><<<256, 256, 0, stream>>>(ench, encl, wsh, wsl, dec,
                                                   nullptr);
}

// Round 8
// 2265.166 us; speedup vs baseline: 1.6606x; 1.6606x over previous
//
#include <hip/hip_runtime.h>

typedef _Float16 half8 __attribute__((ext_vector_type(8)));
typedef _Float16 half4 __attribute__((ext_vector_type(4)));
typedef float floatx4 __attribute__((ext_vector_type(4)));

static constexpr int BATCH = 1024;
static constexpr int NIN   = 512;    // in_features
static constexpr int MOUT  = 1024;   // out_features
static constexpr float LAMBD = 0.2f;
static constexpr float TOLF  = 1e-4f;
static constexpr int MAX_ITERS = 100;
static constexpr int MM = BATCH * MOUT;   // 1M elements

// Fragment-swizzled layout for 16x16x32 MFMA operands (A: rows, B: cols), f16:
//   flat = ((tile16*32 + kchunk32)*64 + lane)*8 + elem
//   lane = (idx&15) | (((k>>3)&3)<<4), elem = k&7
// One (tile16, k32) fragment = 1 KB contiguous chunk in lane order, so a wave
// stages it with a single global_load_lds width-16 (wave-uniform base+lane*16)
// and loads it with one ds_read_b128 per lane.
__device__ __forceinline__ size_t swz(int idx, int k) {
    return ((((size_t)(idx >> 4) * 32 + (k >> 5)) * 64 +
             ((idx & 15) | (((k >> 3) & 3) << 4))) << 3) + (k & 7);
}

__device__ __forceinline__ float shrinkf(float t) {
    float a = fabsf(t) - LAMBD;
    return a > 0.f ? copysignf(a, t) : 0.f;
}

// ---------------------------------------------------------------------------
// zero-init: t, enc, dec, swizzled enc halves, solved  (xkp needs no init)
// ---------------------------------------------------------------------------
__global__ __launch_bounds__(256) void zero_init(float* t, float* enc,
                                                 float* dec, float* ench_f,
                                                 float* encl_f, int* solved) {
    int i = blockIdx.x * 256 + threadIdx.x;
    if (i < MM) { t[i] = 0.f; enc[i] = 0.f; }
    if (i < MM / 2) { dec[i] = 0.f; ench_f[i] = 0.f; encl_f[i] = 0.f; }
    if (i < BATCH) solved[i] = 0;
}

// ---------------------------------------------------------------------------
// Th/Tl = B-fragment-swizzled split-f16 of Minv (col=n in 1024, k in 1024).
// ---------------------------------------------------------------------------
__global__ __launch_bounds__(256) void split_minv(const float* __restrict__ Minv,
                                                  _Float16* __restrict__ Th,
                                                  _Float16* __restrict__ Tl) {
    int g = blockIdx.x * 256 + threadIdx.x;   // 131072 threads
    int n = g & 1023, k0 = (g >> 10) << 3;
    half8 h, l;
    #pragma unroll
    for (int e = 0; e < 8; ++e) {
        float val = Minv[(size_t)(k0 + e) * MOUT + n];
        _Float16 hh = (_Float16)val;
        h[e] = hh;
        l[e] = (_Float16)(val - (float)hh);
    }
    size_t off = swz(n, k0);
    *(half8*)&Th[off] = h;
    *(half8*)&Tl[off] = l;
}

// ---------------------------------------------------------------------------
// wsh/wsl = B-fragment-swizzled split-f16 of weight (col=n in 512, k in 1024).
// ---------------------------------------------------------------------------
__global__ __launch_bounds__(256) void split_w(const float* __restrict__ w,
                                               _Float16* __restrict__ wsh,
                                               _Float16* __restrict__ wsl) {
    int g = blockIdx.x * 256 + threadIdx.x;   // 65536 threads
    int n = g & 511, k0 = (g >> 9) << 3;
    half8 h, l;
    #pragma unroll
    for (int e = 0; e < 8; ++e) {
        float val = w[(size_t)(k0 + e) * NIN + n];
        _Float16 hh = (_Float16)val;
        h[e] = hh;
        l[e] = (_Float16)(val - (float)hh);
    }
    size_t off = swz(n, k0);
    *(half8*)&wsh[off] = h;
    *(half8*)&wsl[off] = l;
}

// ---------------------------------------------------------------------------
// adb = x @ w^T (fp32, once). Epilogue emits beff = adb as A-swizzled h/l.
// ---------------------------------------------------------------------------
__global__ __launch_bounds__(256) void gemm_adb(const float* __restrict__ x,
                                                const float* __restrict__ w,
                                                float* __restrict__ adb,
                                                _Float16* __restrict__ bh,
                                                _Float16* __restrict__ bl) {
    __shared__ float As[16][68];
    __shared__ float Bs[16][68];
    const int tid = threadIdx.x;
    const int i0 = (blockIdx.x >> 4) * 64, j0 = (blockIdx.x & 15) * 64;
    const int tx = tid & 15, ty = tid >> 4;
    const int lr = tid >> 2, lk = (tid & 3) << 2;
    float acc[4][4] = {};
    for (int k0 = 0; k0 < NIN; k0 += 16) {
        float4 a4 = *(const float4*)&x[(i0 + lr) * NIN + k0 + lk];
        As[lk + 0][lr] = a4.x; As[lk + 1][lr] = a4.y;
        As[lk + 2][lr] = a4.z; As[lk + 3][lr] = a4.w;
        float4 b4 = *(const float4*)&w[(j0 + lr) * NIN + k0 + lk];
        Bs[lk + 0][lr] = b4.x; Bs[lk + 1][lr] = b4.y;
        Bs[lk + 2][lr] = b4.z; Bs[lk + 3][lr] = b4.w;
        __syncthreads();
        #pragma unroll
        for (int kk = 0; kk < 16; ++kk) {
            float4 a_ = *(const float4*)&As[kk][ty << 2];
            float4 b_ = *(const float4*)&Bs[kk][tx << 2];
            #pragma unroll
            for (int r = 0; r < 4; ++r) {
                float av = r == 0 ? a_.x : r == 1 ? a_.y : r == 2 ? a_.z : a_.w;
                acc[r][0] = fmaf(av, b_.x, acc[r][0]);
                acc[r][1] = fmaf(av, b_.y, acc[r][1]);
                acc[r][2] = fmaf(av, b_.z, acc[r][2]);
                acc[r][3] = fmaf(av, b_.w, acc[r][3]);
            }
        }
        __syncthreads();
    }
    const int k4 = j0 + (tx << 2);
    #pragma unroll
    for (int r = 0; r < 4; ++r) {
        const int row = i0 + (ty << 2) + r;
        *(float4*)&adb[(size_t)row * MOUT + k4] =
            make_float4(acc[r][0], acc[r][1], acc[r][2], acc[r][3]);
        half4 h, l;
        #pragma unroll
        for (int e = 0; e < 4; ++e) {
            _Float16 hh = (_Float16)acc[r][e];
            h[e] = hh;
            l[e] = (_Float16)(acc[r][e] - (float)hh);
        }
        size_t off = swz(row, k4);
        *(half4*)&bh[off] = h;
        *(half4*)&bl[off] = l;
    }
}

// ---------------------------------------------------------------------------
// Iteration GEMM (m97 pattern): 64x64 tile, S=2 split-K (grid 512, 2 blk/CU),
// BK=32, single LDS buffer staged via global_load_lds width-16 (no ds_writes
// on the wave issue path), 2 barriers/step hidden by the co-resident block.
// 4 waves: each 32x32 quadrant = 2x2 MFMA tiles x 3 split-f16 products.
// Output: deterministic partial per K-chunk into xkp[c] (no atomics).
// ---------------------------------------------------------------------------
__global__ __launch_bounds__(256, 2)
void gemm_xk(const _Float16* __restrict__ bh, const _Float16* __restrict__ bl,
             const _Float16* __restrict__ Th, const _Float16* __restrict__ Tl,
             float* __restrict__ xkp, const int* __restrict__ solved) {
    const int bid = blockIdx.x;
    const int c = bid & 1, t = bid >> 1;
    const int mt = t >> 4, nt = t & 15;
    const int m0 = mt << 6, n0 = nt << 6;
    const int tid = threadIdx.x, lane = tid & 63;

    bool done = ((volatile const int*)solved)[m0 + lane] != 0;
    if (__ballot(done) == ~0ull) return;   // whole 64-row stripe solved

    __shared__ _Float16 Ash[16 * 512];     // 16 KB: 16 chunks (arr<<2 | i)

    const int wv = tid >> 6;
    const int wm = (wv >> 1) & 1, wn = wv & 1;
    const int kf0 = c << 4;                // first k32-chunk of this K-half

    // wave wv stages array wv: 0=Ah(bh) 1=Al(bl) 2=Bh(Th) 3=Bl(Tl)
    const _Float16* sarr = (wv == 0) ? bh : (wv == 1) ? bl : (wv == 2) ? Th : Tl;
    const int stile = (wv < 2) ? (mt << 2) : (nt << 2);

    floatx4 acc[2][2] = {};
    for (int s = 0; s < 16; ++s) {
        // ---- stage step s: 4 chunks of 1 KB per wave
        #pragma unroll
        for (int i = 0; i < 4; ++i) {
            const _Float16* src = sarr +
                ((((size_t)(stile + i) * 32 + kf0 + s) << 9) + ((size_t)lane << 3));
            __builtin_amdgcn_global_load_lds(
                (const __attribute__((address_space(1))) void*)src,
                (__attribute__((address_space(3))) void*)
                    &Ash[(((wv << 2) + i) << 9)],
                16, 0, 0);
        }
        __syncthreads();

        // ---- fragments: A tiles 2*wm+i, B tiles 2*wn+j
        half8 ah[2], al[2], bhf[2], blf[2];
        #pragma unroll
        for (int i = 0; i < 2; ++i) {
            const int at = (wm << 1) + i;
            ah[i]  = *(const half8*)&Ash[((0 << 11) + (at << 9)) + (lane << 3)];
            al[i]  = *(const half8*)&Ash[((1 << 11) + (at << 9)) + (lane << 3)];
            const int bt = (wn << 1) + i;
            bhf[i] = *(const half8*)&Ash[((2 << 11) + (bt << 9)) + (lane << 3)];
            blf[i] = *(const half8*)&Ash[((3 << 11) + (bt << 9)) + (lane << 3)];
        }
        #pragma unroll
        for (int i = 0; i < 2; ++i)
            #pragma unroll
            for (int j = 0; j < 2; ++j) {
                acc[i][j] = __builtin_amdgcn_mfma_f32_16x16x32_f16(
                    ah[i], blf[j], acc[i][j], 0, 0, 0);
                acc[i][j] = __builtin_amdgcn_mfma_f32_16x16x32_f16(
                    al[i], bhf[j], acc[i][j], 0, 0, 0);
                acc[i][j] = __builtin_amdgcn_mfma_f32_16x16x32_f16(
                    ah[i], bhf[j], acc[i][j], 0, 0, 0);
            }
        __syncthreads();
    }

    // C/D: col = lane&15, row = (lane>>4)*4 + reg  [m89 verified]
    float* op = xkp + (size_t)c * MM;
    const int orow = (lane >> 4) << 2;
    #pragma unroll
    for (int i = 0; i < 2; ++i) {
        const int gr = m0 + (wm << 5) + (i << 4) + orow;
        #pragma unroll
        for (int j = 0; j < 2; ++j) {
            const int gc = n0 + (wn << 5) + (j << 4) + (lane & 15);
            #pragma unroll
            for (int r = 0; r < 4; ++r)
                op[(size_t)(gr + r) * MOUT + gc] = acc[i][j][r];
        }
    }
}

// ---------------------------------------------------------------------------
// Row update (t-trick): state is t = xk + u only; v_prev = shrink(t_prev),
// u_prev = t_prev - v_prev (bitwise identical to reference's stored v,u).
// Sums the 2 split-K partials (deterministic order), softshrink, norms,
// freeze; emits beff split h/l; at freeze writes enc + swizzled split enc.
// 1 wave per row, shuffle-only reduction.
// ---------------------------------------------------------------------------
__global__ __launch_bounds__(256) void update(const float* __restrict__ adb,
                                              const float* __restrict__ xkp,
                                              float* __restrict__ t,
                                              _Float16* __restrict__ bh,
                                              _Float16* __restrict__ bl,
                                              float* __restrict__ enc,
                                              _Float16* __restrict__ ench,
                                              _Float16* __restrict__ encl,
                                              int* solved) {
    const int tid = threadIdx.x, lane = tid & 63;
    const int row = (blockIdx.x << 2) + (tid >> 6);
    if (((volatile const int*)solved)[row]) return;   // wave-uniform

    float vn[16];
    float dx2 = 0.f, x2 = 0.f;
    #pragma unroll
    for (int cch = 0; cch < 4; ++cch) {
        const int k4 = (cch << 8) + (lane << 2);
        const size_t j = ((size_t)row << 10) + k4;
        float4 p0 = *(const float4*)&xkp[j];
        float4 p1 = *(const float4*)&xkp[(size_t)MM + j];
        float4 tp = *(const float4*)&t[j];
        float4 aa = *(const float4*)&adb[j];
        float kxa[4] = {p0.x + p1.x, p0.y + p1.y, p0.z + p1.z, p0.w + p1.w};
        float tpa[4] = {tp.x, tp.y, tp.z, tp.w};
        float aaa[4] = {aa.x, aa.y, aa.z, aa.w};
        float tna[4];
        half4 h, l;
        #pragma unroll
        for (int e = 0; e < 4; ++e) {
            float vprev = shrinkf(tpa[e]);
            float uu = tpa[e] - vprev;
            float tn = kxa[e] + uu;          // = u + xk  (ref order)
            float vv = shrinkf(tn);
            float un = tn - vv;              // u_new = (u + xk) - v_new
            float d = vv - vprev;
            dx2 += d * d;
            x2 += vv * vv;
            vn[(cch << 2) + e] = vv;
            tna[e] = tn;
            float nb = (aaa[e] + vv) - un;   // (adb + v_new) - u_new (ref order)
            _Float16 hh = (_Float16)nb;
            h[e] = hh;
            l[e] = (_Float16)(nb - (float)hh);
        }
        *(float4*)&t[j] = make_float4(tna[0], tna[1], tna[2], tna[3]);
        size_t off = swz(row, k4);
        *(half4*)&bh[off] = h;
        *(half4*)&bl[off] = l;
    }
    #pragma unroll
    for (int off = 32; off; off >>= 1) {
        dx2 += __shfl_xor(dx2, off);
        x2  += __shfl_xor(x2, off);
    }
    if (dx2 < TOLF * TOLF * x2) {   // x2==0 -> false (NaN semantics)
        #pragma unroll
        for (int cch = 0; cch < 4; ++cch) {
            const int k4 = (cch << 8) + (lane << 2);
            const size_t j = ((size_t)row << 10) + k4;
            float va[4] = {vn[(cch << 2) + 0], vn[(cch << 2) + 1],
                           vn[(cch << 2) + 2], vn[(cch << 2) + 3]};
            *(float4*)&enc[j] = make_float4(va[0], va[1], va[2], va[3]);
            half4 h, l;
            #pragma unroll
            for (int e = 0; e < 4; ++e) {
                _Float16 hh = (_Float16)va[e];
                h[e] = hh;
                l[e] = (_Float16)(va[e] - (float)hh);
            }
            size_t off = swz(row, k4);
            *(half4*)&ench[off] = h;
            *(half4*)&encl[off] = l;
        }
        if (lane == 0) ((volatile int*)solved)[row] = 1;
    }
}

// ---------------------------------------------------------------------------
// dec = enc @ w, split-f16 MFMA, runs ONCE. 128x128 tile, S=8 whole-partition
// A staging (64 KB), one barrier, atomicAdd epilogue (one-time cost).
// ---------------------------------------------------------------------------
__global__ __launch_bounds__(256, 2)
void mfma_dec(const _Float16* __restrict__ Ahg, const _Float16* __restrict__ Alg,
              const _Float16* __restrict__ Bhg, const _Float16* __restrict__ Blg,
              float* __restrict__ out) {
    constexpr int NSTR = NIN;              // 512
    constexpr int NT = NSTR / 128;         // 4
    const int bid = blockIdx.x;
    const int c = bid & 7, t = bid >> 3;
    const int mt = t / NT, nt = t % NT;
    const int tid = threadIdx.x, lane = tid & 63;

    __shared__ _Float16 Ash[64 * 512];     // 64 KB

    const int wv = tid >> 6;
    const int wm = (tid >> 7) & 1, wn = (tid >> 6) & 1;
    const int kf0 = c << 2;

    #pragma unroll
    for (int i = 0; i < 16; ++i) {
        const int chunk = (wv << 4) + i;
        const int rt = chunk >> 3, kc = (chunk >> 1) & 3, hl = chunk & 1;
        const _Float16* src = (hl ? Alg : Ahg) +
            ((((size_t)((mt << 3) + rt) * 32 + kf0 + kc) << 9) + ((size_t)lane << 3));
        __builtin_amdgcn_global_load_lds(
            (const __attribute__((address_space(1))) void*)src,
            (__attribute__((address_space(3))) void*)&Ash[(size_t)chunk << 9],
            16, 0, 0);
    }
    __syncthreads();

    const int ct0 = nt * 8 + (wn << 2);
    const _Float16* pBh = Bhg + ((((size_t)ct0 * 32 + kf0) * 64 + lane) << 3);
    const _Float16* pBl = Blg + ((((size_t)ct0 * 32 + kf0) * 64 + lane) << 3);

    floatx4 acc[4][4] = {};
    #pragma unroll
    for (int s = 0; s < 4; ++s) {
        half8 bhf[4], blf[4];
        #pragma unroll
        for (int j = 0; j < 4; ++j) {
            bhf[j] = *(const half8*)(pBh + ((size_t)j << 14) + ((size_t)s << 9));
            blf[j] = *(const half8*)(pBl + ((size_t)j << 14) + ((size_t)s << 9));
        }
        half8 ah[4], al[4];
        #pragma unroll
        for (int i = 0; i < 4; ++i) {
            const int rt = (wm << 2) + i;
            ah[i] = *(const half8*)&Ash[((((rt << 2) + s) << 1) << 9) + (lane << 3)];
            al[i] = *(const half8*)&Ash[(((((rt << 2) + s) << 1) + 1) << 9) + (lane << 3)];
        }
        #pragma unroll
        for (int i = 0; i < 4; ++i)
            #pragma unroll
            for (int j = 0; j < 4; ++j) {
                acc[i][j] = __builtin_amdgcn_mfma_f32_16x16x32_f16(
                    ah[i], blf[j], acc[i][j], 0, 0, 0);
                acc[i][j] = __builtin_amdgcn_mfma_f32_16x16x32_f16(
                    al[i], bhf[j], acc[i][j], 0, 0, 0);
                acc[i][j] = __builtin_amdgcn_mfma_f32_16x16x32_f16(
                    ah[i], bhf[j], acc[i][j], 0, 0, 0);
            }
    }

    const int orow = (lane >> 4) << 2;
    #pragma unroll
    for (int i = 0; i < 4; ++i) {
        const int gr = (mt << 7) + (wm << 6) + (i << 4) + orow;
        #pragma unroll
        for (int j = 0; j < 4; ++j) {
            const int gc = nt * 128 + (wn << 6) + (j << 4) + (lane & 15);
            #pragma unroll
            for (int r = 0; r < 4; ++r)
                atomicAdd(&out[(size_t)(gr + r) * NSTR + gc], acc[i][j][r]);
        }
    }
}

// ---------------------------------------------------------------------------
extern "C" void kernel_launch(void* const* d_in, const int* in_sizes, int n_in,
                              void* d_out, int out_size, void* d_ws, size_t ws_size,
                              hipStream_t stream) {
    const float* x    = (const float*)d_in[0];
    const float* w    = (const float*)d_in[1];
    const float* Minv = (const float*)d_in[2];

    float* enc = (float*)d_out;          // encoded: 1024*1024
    float* dec = enc + MM;               // decoded: 1024*512

    // ws (floats): adb MM | t MM | xkp 2*MM | halves: bh,bl,Th,Tl,ench,encl MM,
    // wsh,wsl MM/2 | solved. ~30 MB.
    float* ws  = (float*)d_ws;
    float* adb = ws;
    float* t   = ws + (size_t)MM;
    float* xkp = ws + 2 * (size_t)MM;

    _Float16* bh   = (_Float16*)(ws + 4 * (size_t)MM);
    _Float16* bl   = bh + (size_t)MM;
    _Float16* Th   = bl + (size_t)MM;
    _Float16* Tl   = Th + (size_t)MM;
    _Float16* ench = Tl + (size_t)MM;
    _Float16* encl = ench + (size_t)MM;
    _Float16* wsh  = encl + (size_t)MM;
    _Float16* wsl  = wsh + (size_t)(NIN * MOUT);
    int* solved    = (int*)(wsl + (size_t)(NIN * MOUT));

    zero_init<<<(MM + 255) / 256, 256, 0, stream>>>(t, enc, dec, (float*)ench,
                                                    (float*)encl, solved);
    split_minv<<<512, 256, 0, stream>>>(Minv, Th, Tl);
    split_w<<<256, 256, 0, stream>>>(w, wsh, wsl);
    gemm_adb<<<256, 256, 0, stream>>>(x, w, adb, bh, bl);

    for (int it = 0; it < MAX_ITERS; ++it) {
        gemm_xk<<<512, 256, 0, stream>>>(bh, bl, Th, Tl, xkp, solved);
        update<<<256, 256, 0, stream>>>(adb, xkp, t, bh, bl, enc, ench, encl,
                                        solved);
    }

    mfma_dec<<<256, 256, 0, stream>>>(ench, encl, wsh, wsl, dec);
}